// Round 14
// baseline (75.747 us; speedup 1.0000x reference)
//
#include <hip/hip_runtime.h>
#include <hip/hip_bf16.h>

// ---- problem constants ----
#define B_IMG   128
#define CH      3
#define HW      224
#define NPATCH  196          // tokens per image
#define TOKENS  25088        // B_IMG * NPATCH
#define PATCH   16
#define FDIM    768          // C*P*P (K of the GEMM)
#define DDIM    768          // output embed dim (N of the GEMM)
#define TOKELEMS ((size_t)TOKENS * FDIM)
#define OUT_TOKENS ((size_t)TOKENS * DDIM)     // positions follow in d_out

// brick = (tile16, kt32): 512 shorts = 1KB. Gather: 1568*24 = 37632 bricks;
// W: 48*24 = 1152 bricks. One WAVE per brick -> 1KB coalesced store.
#define GATHER_BRICK_BLOCKS (37632 / 4)   // 9408
#define W_BRICK_BLOCKS      (1152 / 4)    // 288

typedef short short8 __attribute__((ext_vector_type(8)));
typedef float f32x4  __attribute__((ext_vector_type(4)));

static __device__ __forceinline__ unsigned short f2bf(float v) {
  unsigned u = __float_as_uint(v);
  unsigned r = u + 0x7fffu + ((u >> 16) & 1u);
  return (unsigned short)(r >> 16);
}

// ---- kernel 1: gather + W-convert into FRAGMENT-MAJOR bricks (R13 verbatim) ----
// Brick layout (shorts): PF[brick*512 + (lg*16+lr)*8 + e]
//   brick = tile16*24 + kt;  row = tile16*16 + lr;  k = kt*32 + lg*8 + e.
// One WAVE builds one brick -> the store is exactly 64x16B = 1KB contiguous.
__global__ __launch_bounds__(256) void prep_kernel(
    const float* __restrict__ x, const int* __restrict__ ys,
    const int* __restrict__ xs, const float* __restrict__ W,
    short* __restrict__ PF, short* __restrict__ WF,
    float* __restrict__ pos) {
  const int w  = threadIdx.x >> 6;
  const int l  = threadIdx.x & 63;
  const int lr = l & 15;
  const int lg = l >> 4;
  const int k8rem = lg & 3;              // k8 = kt*4 + lg

  if (blockIdx.x < GATHER_BRICK_BLOCKS) {
    const int brick  = blockIdx.x * 4 + w;      // 0..37631
    const int tile16 = brick / 24;
    const int kt     = brick - tile16 * 24;
    const int tok    = tile16 * 16 + lr;
    const int b      = tok / NPATCH;
    const int y      = ys[tok];
    const int xc     = xs[tok];
    const int k8     = kt * 4 + k8rem;          // 0..95
    const int c      = k8 >> 5;
    const int rem    = k8 & 31;
    const int py     = rem >> 1;
    const int px0    = (rem & 1) * 8;
    const float* src = x + (size_t)(b * CH + c) * (HW * HW) +
                       (size_t)(y + py) * HW + xc + px0;
    float4 v0 = *(const float4*)src;
    float4 v1 = *(const float4*)(src + 4);
    short8 o;
    o[0] = (short)f2bf(v0.x); o[1] = (short)f2bf(v0.y);
    o[2] = (short)f2bf(v0.z); o[3] = (short)f2bf(v0.w);
    o[4] = (short)f2bf(v1.x); o[5] = (short)f2bf(v1.y);
    o[6] = (short)f2bf(v1.z); o[7] = (short)f2bf(v1.w);
    *(short8*)&PF[(size_t)brick * 512 + l * 8] = o;   // wave: 1KB contiguous
    if (kt == 0 && lg == 0) {
      pos[(size_t)tok * 2]     = (float)y;
      pos[(size_t)tok * 2 + 1] = (float)xc;
    }
  } else {
    const int brick  = (blockIdx.x - GATHER_BRICK_BLOCKS) * 4 + w;  // 0..1151
    const int tile16 = brick / 24;
    const int kt     = brick - tile16 * 24;
    const int n      = tile16 * 16 + lr;
    const int k8     = kt * 4 + k8rem;
    const float* src = W + (size_t)n * FDIM + k8 * 8;
    float4 v0 = *(const float4*)src;
    float4 v1 = *(const float4*)(src + 4);
    short8 o;
    o[0] = (short)f2bf(v0.x); o[1] = (short)f2bf(v0.y);
    o[2] = (short)f2bf(v0.z); o[3] = (short)f2bf(v0.w);
    o[4] = (short)f2bf(v1.x); o[5] = (short)f2bf(v1.y);
    o[6] = (short)f2bf(v1.z); o[7] = (short)f2bf(v1.w);
    *(short8*)&WF[(size_t)brick * 512 + l * 8] = o;
  }
}

// ---- kernel 2: ZERO-LDS ZERO-BARRIER register GEMM, ring-3 deep pipeline ----
// R13 post-mortem: VGPR=92 proved the compiler collapsed the 2-deep register
// dbuf to depth ~1 (loads issued ~80cyc before use vs ~300cyc L2 latency).
// Fix: ring-3 NAMED sets (rule #20: unrolled x3), loads for step s+3 issued
// TWO full steps ahead (budget ~2 MFMA clusters + waits > L2 latency),
// counted vmcnt(16), sched_barrier(0) pins so the load clusters can't sink.
__global__ __launch_bounds__(256) void gemm_kernel(
    const short* __restrict__ PF,   // fragment-major patches
    const short* __restrict__ WF,   // fragment-major W
    const float* __restrict__ bias,
    float* __restrict__ C) {
  const int tid = threadIdx.x;
  const int w   = tid >> 6;
  const int l   = tid & 63;
  const int lr  = l & 15;
  const int lg  = l >> 4;

  // XCD swizzle (1176 = 8*147, bijective): 12 consecutive jobs share an
  // A row-panel -> same-XCD L2 reuse; block's 4 waves share mt -> A L1 hits.
  const int id  = blockIdx.x;
  const int nid = (id & 7) * 147 + (id >> 3);
  const int job = nid * 4 + w;            // 0..4703
  const int mt  = job / 12;               // 392 M-tiles of 64
  const int nt  = job - mt * 12;          // 12 N-tiles of 64
  const int m0  = mt * 64;
  const int n0  = nt * 64;

  const short* pA = PF + (size_t)(m0 >> 4) * 24 * 512 + l * 8;
  const short* pB = WF + (size_t)(n0 >> 4) * 24 * 512 + l * 8;

  float bs4[4];
#pragma unroll
  for (int ni = 0; ni < 4; ++ni) bs4[ni] = bias[n0 + ni * 16 + lr];
#pragma unroll
  for (int ni = 0; ni < 4; ++ni) asm volatile("" : "+v"(bs4[ni]));

  f32x4 acc[4][4];
  const f32x4 z = {0.f, 0.f, 0.f, 0.f};
#pragma unroll
  for (int mi = 0; mi < 4; ++mi)
#pragma unroll
    for (int ni = 0; ni < 4; ++ni) acc[mi][ni] = z;

  // three named fragment sets (ring-3)
  short8 A0[4], B0[4], A1[4], B1[4], A2[4], B2[4];

#define LOADSET(Af, Bf, KT)                                                  \
  do {                                                                       \
    const size_t ko_ = (size_t)(KT) * 512;                                   \
    _Pragma("unroll")                                                        \
    for (int i = 0; i < 4; ++i)                                              \
      Af[i] = *(const short8*)(pA + (size_t)i * 12288 + ko_);                \
    _Pragma("unroll")                                                        \
    for (int i = 0; i < 4; ++i)                                              \
      Bf[i] = *(const short8*)(pB + (size_t)i * 12288 + ko_);                \
  } while (0)

#define MFMASET(Af, Bf)                                                      \
  do {                                                                       \
    __builtin_amdgcn_s_setprio(1);                                           \
    _Pragma("unroll")                                                        \
    for (int mi = 0; mi < 4; ++mi)                                           \
      _Pragma("unroll")                                                      \
      for (int ni = 0; ni < 4; ++ni)                                         \
        acc[mi][ni] = __builtin_amdgcn_mfma_f32_16x16x32_bf16(               \
            Af[mi], Bf[ni], acc[mi][ni], 0, 0, 0);                           \
    __builtin_amdgcn_s_setprio(0);                                           \
  } while (0)

  // one pipeline stage: wait set landed (2 younger sets in flight), MFMA it,
  // refill the just-freed buffer with the set 3 steps ahead.
#define STEP3(Af, Bf, KTNEXT)                                                \
  do {                                                                       \
    asm volatile("s_waitcnt vmcnt(16)" ::: "memory");                        \
    __builtin_amdgcn_sched_barrier(0);                                       \
    MFMASET(Af, Bf);                                                         \
    LOADSET(Af, Bf, (KTNEXT));                                               \
    __builtin_amdgcn_sched_barrier(0);                                       \
  } while (0)

  // prologue: 3 sets in flight (24 loads outstanding)
  LOADSET(A0, B0, 0);
  LOADSET(A1, B1, 1);
  LOADSET(A2, B2, 2);
  __builtin_amdgcn_sched_barrier(0);

  // main: 7 triples cover steps 0..20, issuing loads for 3..23
#pragma unroll 1
  for (int t = 0; t < 21; t += 3) {
    STEP3(A0, B0, t + 3);
    STEP3(A1, B1, t + 4);
    STEP3(A2, B2, t + 5);
  }
  // tail: steps 21,22,23 (no more loads; drain 16 -> 8 -> 0)
  asm volatile("s_waitcnt vmcnt(16)" ::: "memory");
  __builtin_amdgcn_sched_barrier(0);
  MFMASET(A0, B0);
  asm volatile("s_waitcnt vmcnt(8)" ::: "memory");
  __builtin_amdgcn_sched_barrier(0);
  MFMASET(A1, B1);
  asm volatile("s_waitcnt vmcnt(0)" ::: "memory");
  __builtin_amdgcn_sched_barrier(0);
  MFMASET(A2, B2);

  // epilogue: C/D layout col = lane&15, row = (lane>>4)*4 + j
#pragma unroll
  for (int ni = 0; ni < 4; ++ni) {
    const int col = n0 + ni * 16 + lr;
#pragma unroll
    for (int mi = 0; mi < 4; ++mi) {
      const int row = m0 + mi * 16 + lg * 4;
      const f32x4 v = acc[mi][ni];
#pragma unroll
      for (int j = 0; j < 4; ++j)
        C[(size_t)(row + j) * DDIM + col] = v[j] + bs4[ni];
    }
  }
#undef LOADSET
#undef MFMASET
#undef STEP3
}

// ---- fallback (ws too small): naive fused f32, correct but slow ----
__global__ __launch_bounds__(256) void naive_kernel(
    const float* __restrict__ x, const int* __restrict__ ys,
    const int* __restrict__ xs, const float* __restrict__ W,
    const float* __restrict__ bias, float* __restrict__ out) {
  __shared__ float prow[FDIM];
  const int tok = blockIdx.x;
  const int t   = threadIdx.x;
  const int b   = tok / NPATCH;
  const int y   = ys[tok];
  const int xc  = xs[tok];
  for (int i = t; i < FDIM; i += 256) {
    int c = i >> 8, rem = i & 255, py = rem >> 4, px = rem & 15;
    prow[i] = x[((size_t)(b * CH + c) * HW + y + py) * HW + xc + px];
  }
  __syncthreads();
  for (int dd = 0; dd < 3; ++dd) {
    const int d = t + dd * 256;
    float s = bias[d];
    const float4* wr = (const float4*)&W[(size_t)d * FDIM];
    const float4* pr = (const float4*)prow;
    for (int f4 = 0; f4 < FDIM / 4; ++f4) {
      float4 wv = wr[f4];
      float4 pv = pr[f4];
      s += wv.x * pv.x + wv.y * pv.y + wv.z * pv.z + wv.w * pv.w;
    }
    out[(size_t)tok * DDIM + d] = s;
  }
  if (t == 0) {
    float* pos = out + OUT_TOKENS;
    pos[(size_t)tok * 2]     = (float)y;
    pos[(size_t)tok * 2 + 1] = (float)xc;
  }
}

extern "C" void kernel_launch(void* const* d_in, const int* in_sizes, int n_in,
                              void* d_out, int out_size, void* d_ws, size_t ws_size,
                              hipStream_t stream) {
  const float* x    = (const float*)d_in[0];
  const int*   ys   = (const int*)d_in[1];
  const int*   xs   = (const int*)d_in[2];
  const float* W    = (const float*)d_in[3];
  const float* bias = (const float*)d_in[4];
  float* out = (float*)d_out;
  float* pos = out + OUT_TOKENS;

  const size_t w_bytes = (size_t)DDIM * FDIM * 2;   // WF: 1,179,648
  const size_t p_bytes = TOKELEMS * 2;              // PF: 38,535,168
  if (ws_size >= w_bytes + p_bytes) {
    short* WF = (short*)d_ws;
    short* PF = (short*)d_ws + (size_t)DDIM * FDIM;
    prep_kernel<<<GATHER_BRICK_BLOCKS + W_BRICK_BLOCKS, 256, 0, stream>>>(
        x, ys, xs, W, PF, WF, pos);
    gemm_kernel<<<1176, 256, 0, stream>>>(PF, WF, bias, out);
  } else {
    naive_kernel<<<TOKENS, 256, 0, stream>>>(x, ys, xs, W, bias, out);
  }
}